// Round 1
// baseline (65.658 us; speedup 1.0000x reference)
//
#include <hip/hip_runtime.h>

// Problem constants (from reference): B=32, N=2048, OUT=100
#define BATCH  32
#define NDIM   2048
#define NOUT   100
#define SPLIT  8                 // j-slices per batch row
#define SLICE  (NDIM / SPLIT)    // 256
#define BLOCK  256

// out[b,o] = sum_j rem[b,j] * W[j,o]
// rem[b,j] = (q[b,j] - (N*c[b,j] + S[b]))^2,  c = (int)q, S[b] = sum_j c[b,j]
__global__ __launch_bounds__(BLOCK)
void fused_model_kernel(const float* __restrict__ q,
                        const float* __restrict__ W,
                        float* __restrict__ out)
{
    const int s = blockIdx.x;   // j-slice index [0,SPLIT)
    const int b = blockIdx.y;   // batch row
    const int t = threadIdx.x;

    __shared__ float rem_lds[SLICE];       // this slice's rem values
    __shared__ int   red[BLOCK];           // int-sum reduction
    __shared__ float half_partial[128];    // cross-half combine

    const float* qrow = q + b * NDIM;

    // ---- Phase 1: load full row (coalesced), cast, row-sum S ----
    int   csum  = 0;
    float q_mine = 0.f;
    int   c_mine = 0;
    #pragma unroll
    for (int k = 0; k < SPLIT; ++k) {
        float v = qrow[k * SLICE + t];     // lane-contiguous loads
        int   c = (int)v;                  // trunc-toward-zero == jnp astype(int32)
        csum += c;
        if (k == s) { q_mine = v; c_mine = c; }
    }
    red[t] = csum;
    __syncthreads();
    #pragma unroll
    for (int w = BLOCK / 2; w > 0; w >>= 1) {
        if (t < w) red[t] += red[t + w];
        __syncthreads();
    }
    const int S = red[0];                  // valid: last iteration ended with barrier

    // ---- rem for this block's slice (exact: |N*c + S| << 2^24) ----
    {
        float d = q_mine - (float)(NDIM * c_mine + S);
        rem_lds[t] = d * d;
    }
    __syncthreads();

    // ---- Phase 2: partial GEMV vs W[s*SLICE : (s+1)*SLICE, :] ----
    const int o = t & 127;      // output column
    const int h = t >> 7;       // which half of the slice's j-range
    float acc = 0.f;
    if (o < NOUT) {
        const int jbeg = h * (SLICE / 2);
        const float* Wbase = W + (size_t)(s * SLICE) * NOUT + o;
        #pragma unroll 4
        for (int j = 0; j < SLICE / 2; ++j) {
            acc += rem_lds[jbeg + j] * Wbase[(size_t)(jbeg + j) * NOUT];
        }
    }
    if (h == 1 && o < NOUT) half_partial[o] = acc;
    __syncthreads();
    if (h == 0 && o < NOUT) {
        acc += half_partial[o];
        atomicAdd(&out[b * NOUT + o], acc);   // 8 slices accumulate per output
    }
}

extern "C" void kernel_launch(void* const* d_in, const int* in_sizes, int n_in,
                              void* d_out, int out_size, void* d_ws, size_t ws_size,
                              hipStream_t stream) {
    const float* q = (const float*)d_in[0];   // [32, 2048] f32
    const float* W = (const float*)d_in[1];   // [2048, 100] f32
    float* out = (float*)d_out;               // [32, 100] f32

    // d_out is re-poisoned before every call; atomics need zeros.
    hipMemsetAsync(out, 0, (size_t)out_size * sizeof(float), stream);

    dim3 grid(SPLIT, BATCH);
    fused_model_kernel<<<grid, BLOCK, 0, stream>>>(q, W, out);
}

// Round 2
// 60.027 us; speedup vs baseline: 1.0938x; 1.0938x over previous
//
#include <hip/hip_runtime.h>

// Problem constants (from reference): B=32, N=2048, OUT=100
#define BATCH  32
#define NDIM   2048
#define NOUT   100
#define SPLIT  16                // j-slices per batch row
#define SLICE  (NDIM / SPLIT)    // 128
#define BLOCK  256

// out[b,o] = sum_j rem[b,j] * W[j,o]
// rem[b,j] = (q[b,j] - (N*c[b,j] + S[b]))^2,  c = (int)q, S[b] = sum_j c[b,j]
//
// Grid = (SPLIT, BATCH) = 512 blocks (2/CU). Each block:
//   phase 1: whole row loaded cooperatively, exact int row-sum S via
//            wave-shuffle butterfly + tiny LDS combine (2 barriers total)
//   phase 2: 128-wide j-slice GEMV partial vs W, o lane-contiguous
//            (coalesced), 64-iteration inner loop, atomicAdd into out.
__global__ __launch_bounds__(BLOCK)
void fused_model_kernel(const float* __restrict__ q,
                        const float* __restrict__ W,
                        float* __restrict__ out)
{
    const int s = blockIdx.x;   // j-slice index [0,SPLIT)
    const int b = blockIdx.y;   // batch row
    const int t = threadIdx.x;

    __shared__ float rem_lds[SLICE];        // this slice's rem values
    __shared__ int   wave_sum[BLOCK / 64];  // per-wave int sums
    __shared__ float half_partial[128];     // cross-half combine
    __shared__ int   S_lds;

    const float* qrow = q + b * NDIM;

    // ---- Phase 1: exact row-sum of (int)q ----
    int csum = 0;
    #pragma unroll
    for (int k = 0; k < NDIM / BLOCK; ++k)
        csum += (int)qrow[k * BLOCK + t];   // trunc == jnp astype(int32)

    // 64-lane butterfly
    #pragma unroll
    for (int m = 32; m > 0; m >>= 1)
        csum += __shfl_xor(csum, m, 64);
    if ((t & 63) == 0) wave_sum[t >> 6] = csum;
    __syncthreads();
    if (t == 0) {
        int ssum = 0;
        #pragma unroll
        for (int w = 0; w < BLOCK / 64; ++w) ssum += wave_sum[w];
        S_lds = ssum;
    }
    __syncthreads();
    const int S = S_lds;

    // ---- rem for this block's 128-wide slice (exact: |N*c+S| << 2^24) ----
    if (t < SLICE) {
        float v = qrow[s * SLICE + t];       // L1-warm reload
        int   c = (int)v;
        float d = v - (float)(NDIM * c + S);
        rem_lds[t] = d * d;
    }
    __syncthreads();

    // ---- Phase 2: partial GEMV vs W[s*SLICE : (s+1)*SLICE, :] ----
    const int o = t & 127;      // output column (lane-contiguous -> coalesced)
    const int h = t >> 7;       // which half of the slice's j-range
    float acc = 0.f;
    if (o < NOUT) {
        const int jbeg = h * (SLICE / 2);
        const float* Wbase = W + (size_t)(s * SLICE + jbeg) * NOUT + o;
        #pragma unroll 8
        for (int j = 0; j < SLICE / 2; ++j) {
            acc += rem_lds[jbeg + j] * Wbase[(size_t)j * NOUT];
        }
    }
    if (h == 1 && o < NOUT) half_partial[o] = acc;
    __syncthreads();
    if (h == 0 && o < NOUT) {
        acc += half_partial[o];
        atomicAdd(&out[b * NOUT + o], acc);  // 16 slices accumulate per output
    }
}

extern "C" void kernel_launch(void* const* d_in, const int* in_sizes, int n_in,
                              void* d_out, int out_size, void* d_ws, size_t ws_size,
                              hipStream_t stream) {
    const float* q = (const float*)d_in[0];   // [32, 2048] f32
    const float* W = (const float*)d_in[1];   // [2048, 100] f32
    float* out = (float*)d_out;               // [32, 100] f32

    // d_out is re-poisoned before every call; atomics need zeros.
    hipMemsetAsync(out, 0, (size_t)out_size * sizeof(float), stream);

    dim3 grid(SPLIT, BATCH);
    fused_model_kernel<<<grid, BLOCK, 0, stream>>>(q, W, out);
}

// Round 3
// 59.768 us; speedup vs baseline: 1.0985x; 1.0043x over previous
//
#include <hip/hip_runtime.h>

// Problem constants (from reference): B=32, N=2048, OUT=100
#define BATCH  32
#define NDIM   2048
#define NOUT   100
#define OG     8                  // outputs per block
#define NOG    13                 // ceil(NOUT / OG)
#define BLOCK  256
#define NCHUNK (BLOCK / OG)       // 32 j-chunks
#define CHUNK  (NDIM / NCHUNK)    // 64 j per chunk

// out[b,o] = sum_j rem[b,j] * W[j,o]
// rem[b,j] = (q[b,j] - (N*c[b,j] + S[b]))^2,  c = (int)q, S[b] = sum_j c[b,j]
//
// Single dispatch, no atomics, no memset: each block owns (batch b, 8 output
// columns) and reduces the full j-range internally; every out element gets
// exactly one plain store.
__global__ __launch_bounds__(BLOCK)
void fused_model_kernel(const float* __restrict__ q,
                        const float* __restrict__ W,
                        float* __restrict__ out)
{
    const int g = blockIdx.x;   // output-group index [0,NOG)
    const int b = blockIdx.y;   // batch row
    const int t = threadIdx.x;

    __shared__ float rem_lds[NDIM];     // 8 KB: full row's rem
    __shared__ int   wave_sum[BLOCK / 64];
    __shared__ float wred[BLOCK / 64][OG];
    __shared__ int   S_lds;

    // ---- Phase 1: float4 row load (coalesced); exact int row-sum S ----
    const float4* qrow4 = (const float4*)(q + b * NDIM);
    const float4 v0 = qrow4[t];          // elements 4t .. 4t+3
    const float4 v1 = qrow4[BLOCK + t];  // elements 1024+4t ..

    const int c0x = (int)v0.x, c0y = (int)v0.y, c0z = (int)v0.z, c0w = (int)v0.w;
    const int c1x = (int)v1.x, c1y = (int)v1.y, c1z = (int)v1.z, c1w = (int)v1.w;
    int csum = c0x + c0y + c0z + c0w + c1x + c1y + c1z + c1w;

    #pragma unroll
    for (int m = 32; m > 0; m >>= 1) csum += __shfl_xor(csum, m, 64);
    if ((t & 63) == 0) wave_sum[t >> 6] = csum;
    __syncthreads();
    if (t == 0)
        S_lds = wave_sum[0] + wave_sum[1] + wave_sum[2] + wave_sum[3];
    __syncthreads();
    const int S = S_lds;

    // ---- rem for the 8 elements this thread already holds (exact int math,
    //      |N*c + S| << 2^24 so the float conversion is exact) ----
    {
        const int j0 = 4 * t, j1 = 4 * BLOCK + 4 * t;
        float d;
        d = v0.x - (float)(NDIM * c0x + S); rem_lds[j0 + 0] = d * d;
        d = v0.y - (float)(NDIM * c0y + S); rem_lds[j0 + 1] = d * d;
        d = v0.z - (float)(NDIM * c0z + S); rem_lds[j0 + 2] = d * d;
        d = v0.w - (float)(NDIM * c0w + S); rem_lds[j0 + 3] = d * d;
        d = v1.x - (float)(NDIM * c1x + S); rem_lds[j1 + 0] = d * d;
        d = v1.y - (float)(NDIM * c1y + S); rem_lds[j1 + 1] = d * d;
        d = v1.z - (float)(NDIM * c1z + S); rem_lds[j1 + 2] = d * d;
        d = v1.w - (float)(NDIM * c1w + S); rem_lds[j1 + 3] = d * d;
    }
    __syncthreads();

    // ---- Phase 2: 8 outputs x 32 chunks of 64 j each ----
    const int o    = t & (OG - 1);        // output within group (lane bits 0-2)
    const int ch   = t >> 3;              // j-chunk [0,32)
    const int ocol = g * OG + o;
    const int jb   = ch * CHUNK;

    float acc = 0.f;
    if (ocol < NOUT) {
        const float* Wb = W + (size_t)jb * NOUT + ocol;
        #pragma unroll 8
        for (int j = 0; j < CHUNK; ++j)
            acc += rem_lds[jb + j] * Wb[(size_t)j * NOUT];
    }

    // Reduce over chunks within each wave: lane bits 3-5 (never mixes o).
    acc += __shfl_xor(acc, 8, 64);
    acc += __shfl_xor(acc, 16, 64);
    acc += __shfl_xor(acc, 32, 64);
    if ((t & 63) < OG) wred[t >> 6][o] = acc;
    __syncthreads();

    // Combine the 4 waves; one plain store per output element.
    if (t < OG) {
        const int oc = g * OG + t;
        if (oc < NOUT)
            out[b * NOUT + oc] = wred[0][t] + wred[1][t] + wred[2][t] + wred[3][t];
    }
}

extern "C" void kernel_launch(void* const* d_in, const int* in_sizes, int n_in,
                              void* d_out, int out_size, void* d_ws, size_t ws_size,
                              hipStream_t stream) {
    const float* q = (const float*)d_in[0];   // [32, 2048] f32
    const float* W = (const float*)d_in[1];   // [2048, 100] f32
    float* out = (float*)d_out;               // [32, 100] f32

    dim3 grid(NOG, BATCH);                    // 13 x 32 = 416 blocks
    fused_model_kernel<<<grid, BLOCK, 0, stream>>>(q, W, out);
}